// Round 4
// baseline (15503.900 us; speedup 1.0000x reference)
//
#include <hip/hip_runtime.h>
#include <cstddef>
#include <cstdint>
#include <math.h>

// B=64, T=512, V=50002, E=300, H=256, K=11, START=9, STOP=10
// Output: [64 score][64*512 path] floats = 32832.

__device__ __forceinline__ float sigmf_(float x){ return 1.0f/(1.0f+expf(-x)); }

// raw workgroup barrier: LDS-visibility only (no vmcnt drain -> store acks stay
// off the barrier path). sched_barrier fences stop hoisting across it (rule #18).
__device__ __forceinline__ void bar_sync(){
  __builtin_amdgcn_sched_barrier(0);
  asm volatile("s_waitcnt lgkmcnt(0)" ::: "memory");
  __builtin_amdgcn_s_barrier();
  __builtin_amdgcn_sched_barrier(0);
}

// ---------------- generic zero ----------------
__global__ void k_zero(float* __restrict__ p, int n){
  for (int i = blockIdx.x*blockDim.x + threadIdx.x; i < n; i += gridDim.x*blockDim.x) p[i] = 0.f;
}

// ---------------- gather embeddings slab: X[C*T,304] zero-padded ----------------
__global__ void k_gather(const int* __restrict__ sent, const float* __restrict__ emb,
                         float4* __restrict__ X, int b0, int t0, int logT, int Tm1, int total){
  int idx = blockIdx.x*256 + threadIdx.x;
  if (idx >= total) return;
  int m = idx / 76, k4 = idx - m*76;
  int bl = m >> logT, t = m & Tm1;
  float4 v = make_float4(0.f,0.f,0.f,0.f);
  if (k4 < 75) v = ((const float4*)emb)[(size_t)sent[(size_t)(b0+bl)*512 + t0 + t]*75 + k4];
  X[idx] = v;
}

// ---------------- transpose w_ih into wT [dinPad,1024] ----------------
__global__ void k_prepw(const float* __restrict__ w, float* __restrict__ wT, int din, int dinPad){
  int total = dinPad*1024;
  for (int idx = blockIdx.x*blockDim.x + threadIdx.x; idx < total; idx += gridDim.x*blockDim.x){
    int k = idx >> 10, n = idx & 1023;
    wT[idx] = (k < din) ? w[n*din + k] : 0.f;
  }
}

// ------- dual fp32 GEMM (z=0/1): C[M,1024] = A[M(strided rows),lda] @ Bm[K,1024] + bias -------
__global__ __launch_bounds__(256) void k_gemm2(
    const float* __restrict__ A0, const float* __restrict__ A1, int lda, int kTiles,
    int aBstride, int sOff0, int sOff1, int logT, int Tm1,
    const float* __restrict__ B0, const float* __restrict__ B1,
    const float* __restrict__ bias0, const float* __restrict__ bias1,
    float* __restrict__ C0, float* __restrict__ C1){
  __shared__ float As[16][132];
  __shared__ float Bs[16][132];
  const int z = blockIdx.z;
  const float* A   = z ? A1 : A0;
  const float* Bm  = z ? B1 : B0;
  const float* bias= z ? bias1 : bias0;
  float* Cc        = z ? C1 : C0;
  const int sOff   = z ? sOff1 : sOff0;
  const int t  = threadIdx.x;
  const int tx = t & 15, ty = t >> 4;
  const int m0 = blockIdx.y * 128, n0 = blockIdx.x * 128;
  const int arow = t >> 2, ak = (t & 3) * 4;
  const int brow = t >> 5, bc = (t & 31) * 4;
  const int gm0 = m0 + arow, gm1 = m0 + arow + 64;
  const size_t r0 = (size_t)(gm0 >> logT)*aBstride + sOff + (gm0 & Tm1);
  const size_t r1 = (size_t)(gm1 >> logT)*aBstride + sOff + (gm1 & Tm1);
  float acc[8][8] = {};
  for (int kt = 0; kt < kTiles; ++kt){
    const int kb = kt * 16;
    float4 a0 = *(const float4*)(A + r0*lda + kb + ak);
    float4 a1 = *(const float4*)(A + r1*lda + kb + ak);
    float4 b0 = *(const float4*)(Bm + (size_t)(kb+brow)*1024 + n0 + bc);
    float4 b1 = *(const float4*)(Bm + (size_t)(kb+brow+8)*1024 + n0 + bc);
    __syncthreads();
    As[ak+0][arow] = a0.x; As[ak+1][arow] = a0.y; As[ak+2][arow] = a0.z; As[ak+3][arow] = a0.w;
    As[ak+0][arow+64] = a1.x; As[ak+1][arow+64] = a1.y; As[ak+2][arow+64] = a1.z; As[ak+3][arow+64] = a1.w;
    *(float4*)&Bs[brow  ][bc] = b0;
    *(float4*)&Bs[brow+8][bc] = b1;
    __syncthreads();
    #pragma unroll
    for (int k = 0; k < 16; ++k){
      float av[8], bv[8];
      *(float4*)&av[0] = *(const float4*)&As[k][ty*8];
      *(float4*)&av[4] = *(const float4*)&As[k][ty*8+4];
      *(float4*)&bv[0] = *(const float4*)&Bs[k][tx*8];
      *(float4*)&bv[4] = *(const float4*)&Bs[k][tx*8+4];
      #pragma unroll
      for (int i = 0; i < 8; ++i)
        #pragma unroll
        for (int jj = 0; jj < 8; ++jj)
          acc[i][jj] = fmaf(av[i], bv[jj], acc[i][jj]);
    }
  }
  float bvals[8];
  *(float4*)&bvals[0] = *(const float4*)(bias + n0 + tx*8);
  *(float4*)&bvals[4] = *(const float4*)(bias + n0 + tx*8 + 4);
  float* Cp = Cc + (size_t)(m0 + ty*8)*1024 + n0 + tx*8;
  #pragma unroll
  for (int i = 0; i < 8; ++i){
    float4 o0 = make_float4(acc[i][0]+bvals[0], acc[i][1]+bvals[1], acc[i][2]+bvals[2], acc[i][3]+bvals[3]);
    float4 o1 = make_float4(acc[i][4]+bvals[4], acc[i][5]+bvals[5], acc[i][6]+bvals[6], acc[i][7]+bvals[7]);
    *(float4*)(Cp + (size_t)i*1024)     = o0;
    *(float4*)(Cp + (size_t)i*1024 + 4) = o1;
  }
}

// ---------------- LSTM recurrence: R4 two-barrier stamped-exchange protocol ----------------
// DELTA vs R3 (math/FMA order byte-identical -> bitwise-same results):
//  1) gate-quad-per-wave remap: lane l of wave w owns gate row
//     (l>>4)*256 + hh*128 + (w*16 + (l&15)). h_j's {i,f,g,o} live in ONE wave ->
//     h-update via 3 __shfl; gls buffer + its barrier DELETED (2 barriers/step).
//  2) stamped exchange: h published as one 8B relaxed atomic {stamp32,h32} ->
//     data IS the flag; no separate flag store, no drain-before-flag, one
//     coherence hop instead of two. Parity double-buffer kept (slot s&1).
//  3) raw barriers (lgkmcnt(0)+s_barrier): no implicit vmcnt(0) -> hob/hxme
//     store acks off the barrier path.
//  4) wave0 polls AFTER its local-half FMA: partner stamp is ~1 FMA-phase old
//     by then -> near-zero spin.
// Per-step: [A]local FMA | [B]wave0 poll+LDS-write, Ba | [C]remote FMA |
//           [D]shfl h-update, publish | [E]bar.
__global__ __launch_bounds__(512) __attribute__((amdgpu_waves_per_eu(2, 2)))
void k_lstm2s(
    const float* __restrict__ xwF, const float* __restrict__ xwB,
    const float* __restrict__ whhf, const float* __restrict__ whhb,
    float* __restrict__ hout, int hBstride, int tOffF, int tOffB,
    int T, int epoch,
    unsigned long long* __restrict__ hx,
    float* __restrict__ hsave, float* __restrict__ csave)
{
  __shared__ float hfull[256];
  __shared__ float wtail[512*66];       // 135 KB: per-thread 64-float W tail (q=24..31)
  const int blk = blockIdx.x;
  const int hh = (blk >> 3) & 1;                    // partner = blk ^ 8 (same XCD mod 8)
  const int chain = (blk & 7) | ((blk >> 4) << 3);  // bijection over [0, NB/2)
  const int b_local = chain >> 1;
  const int dir = chain & 1;
  const int t = threadIdx.x;
  const int w = t >> 6, l = t & 63;
  const int gateK = l >> 4;                 // i,f,g,o = 0,1,2,3 within each wave
  const int i0 = w*16 + (l & 15);           // h index within this block's half
  float4 wL[24], wR[24];
  {
    const float* whh = dir ? whhb : whhf;
    const float* base = whh + (size_t)(gateK*256 + hh*128 + i0)*256;
    const float* a = base + hh*128;        // local k-half (this block's h slice)
    const float* b = base + (1-hh)*128;    // remote k-half
    #pragma unroll
    for (int q = 0; q < 24; ++q){ wL[q] = *(const float4*)(a + q*4); wR[q] = *(const float4*)(b + q*4); }
    for (int q = 24; q < 32; ++q){
      #pragma unroll
      for (int e = 0; e < 4; ++e){
        wtail[t*66 + (q-24)*4 + e]      = a[q*4 + e];
        wtail[t*66 + 32 + (q-24)*4 + e] = b[q*4 + e];
      }
    }
  }
  if (t < 256) hfull[t] = hsave[chain*256 + t];
  float c = (l < 16) ? csave[chain*256 + hh*128 + i0] : 0.f;
  __syncthreads();
  const int xcol = gateK*256 + hh*128 + i0;
  const float* xb = (dir ? xwB : xwF) + (size_t)b_local*T*1024 + xcol;
  unsigned long long* hxme       = hx + (size_t)(chain*2 + hh)*256;      // 2 parities x 128 u64
  const unsigned long long* hxpt = hx + (size_t)(chain*2 + (1-hh))*256;
  const int tOff = dir ? tOffB : tOffF;
  float* hob = hout + (size_t)b_local*hBstride + dir*256 + hh*128;
  const float* wtb = &wtail[t*66];
  const float4* hL4 = ((const float4*)hfull) + hh*32;
  const float4* hR4 = ((const float4*)hfull) + (1-hh)*32;
  float xg = xb[(size_t)(dir ? (T-1) : 0)*1024];
  float hlast = 0.f;
  for (int s = 0; s < T; ++s){
    const int tt = dir ? (T-1-s) : s;
    float xn = 0.f;
    if (s < T-1) xn = xb[(size_t)(dir ? (T-2-s) : (s+1))*1024];   // prefetch
    // ---- [A] local-half partial (same sequential FMA order as R3) ----
    float pa = 0.f;
    #pragma unroll
    for (int q = 0; q < 24; ++q){
      float4 hv = hL4[q];                       // wave-uniform -> LDS broadcast
      pa = fmaf(wL[q].x, hv.x, pa);
      pa = fmaf(wL[q].y, hv.y, pa);
      pa = fmaf(wL[q].z, hv.z, pa);
      pa = fmaf(wL[q].w, hv.w, pa);
    }
    #pragma unroll
    for (int q = 24; q < 32; ++q){
      float4 hv = hL4[q];
      const int o = (q-24)*4;
      pa = fmaf(wtb[o+0], hv.x, pa);
      pa = fmaf(wtb[o+1], hv.y, pa);
      pa = fmaf(wtb[o+2], hv.z, pa);
      pa = fmaf(wtb[o+3], hv.w, pa);
    }
    // ---- [B] wave0: acquire partner h(s) (stamped 8B words), write LDS remote ----
    if (s > 0 && w == 0){
      const unsigned long long* src = hxpt + (size_t)(((s-1)&1))*128;
      const unsigned want = (unsigned)(epoch + s);
      unsigned long long v0 = 0, v1 = 0;
      bool ok0 = false, ok1 = false;
      int lim = 0;
      do {
        if (!ok0){ v0 = __hip_atomic_load(src + 2*l,     __ATOMIC_RELAXED, __HIP_MEMORY_SCOPE_AGENT);
                   ok0 = (unsigned)(v0 >> 32) == want; }
        if (!ok1){ v1 = __hip_atomic_load(src + 2*l + 1, __ATOMIC_RELAXED, __HIP_MEMORY_SCOPE_AGENT);
                   ok1 = (unsigned)(v1 >> 32) == want; }
      } while (__any(!(ok0 && ok1)) && ++lim < (1<<20));   // bounded spin (hang fuse)
      hfull[(1-hh)*128 + 2*l]     = __uint_as_float((unsigned)v0);
      hfull[(1-hh)*128 + 2*l + 1] = __uint_as_float((unsigned)v1);
    }
    bar_sync();                               // Ba: remote h(s) visible in LDS
    // ---- [C] remote-half partial ----
    float pb = 0.f;
    #pragma unroll
    for (int q = 0; q < 24; ++q){
      float4 hv = hR4[q];
      pb = fmaf(wR[q].x, hv.x, pb);
      pb = fmaf(wR[q].y, hv.y, pb);
      pb = fmaf(wR[q].z, hv.z, pb);
      pb = fmaf(wR[q].w, hv.w, pb);
    }
    #pragma unroll
    for (int q = 24; q < 32; ++q){
      float4 hv = hR4[q];
      const int o = (q-24)*4;
      pb = fmaf(wtb[32+o+0], hv.x, pb);
      pb = fmaf(wtb[32+o+1], hv.y, pb);
      pb = fmaf(wtb[32+o+2], hv.z, pb);
      pb = fmaf(wtb[32+o+3], hv.w, pb);
    }
    float acc = (pa + pb) + xg;               // == R3 bitwise
    float act = (gateK == 2) ? tanhf(acc) : sigmf_(acc);   // i,f,o sigmoid; g tanh
    // ---- [D] wave-local h-update via shuffles (i@l, f@l+16, g@l+32, o@l+48) ----
    float fg = __shfl(act, (l & 15) + 16, 64);
    float gg = __shfl(act, (l & 15) + 32, 64);
    float og = __shfl(act, (l & 15) + 48, 64);
    if (l < 16){
      c = fg*c + act*gg;                      // same mult order as gls version
      float hval = og*tanhf(c);
      hlast = hval;
      hfull[hh*128 + i0] = hval;              // next step's local half
      unsigned long long pk = ((unsigned long long)(unsigned)(epoch + s + 1) << 32)
                            | (unsigned long long)__float_as_uint(hval);
      __hip_atomic_store(&hxme[(size_t)(s & 1)*128 + i0], pk,
                         __ATOMIC_RELAXED, __HIP_MEMORY_SCOPE_AGENT);
      hob[(size_t)(tOff + tt)*512 + i0] = hval;
    }
    bar_sync();                               // [E]: hfull local h(s+1) visible
    xg = xn;
  }
  if (l < 16){
    hsave[chain*256 + hh*128 + i0] = hlast;
    csave[chain*256 + hh*128 + i0] = c;
  }
}

// ---------------- feats accumulation (one dir half per call) ----------------
__global__ __launch_bounds__(256) void k_feats_half(
    const float* __restrict__ h1s, const float* __restrict__ fcw, const float* __restrict__ fcb,
    float* __restrict__ feats, int b0, int logT, int Tm1, int tG0, int dir){
  int wv = threadIdx.x >> 6, lane = threadIdx.x & 63;
  int m = blockIdx.x*4 + wv;                 // m = bl*T + tl
  const float4* row = (const float4*)(h1s + (size_t)m*512 + dir*256);
  float4 rv = row[lane];
  int bl = m >> logT, tl = m & Tm1;
  size_t fbase = ((size_t)(b0 + bl)*512 + tG0 + tl)*11;
  #pragma unroll
  for (int n = 0; n < 11; ++n){
    const float4* wr = (const float4*)(fcw + n*512 + dir*256);
    float4 w4 = wr[lane];
    float p = rv.x*w4.x + rv.y*w4.y + rv.z*w4.z + rv.w*w4.w;
    #pragma unroll
    for (int off = 32; off > 0; off >>= 1) p += __shfl_down(p, off, 64);
    if (lane == 0){
      float add = (dir == 0) ? (p + fcb[n]) : p;
      feats[fbase + n] += add;
    }
  }
}

// ---------------- Viterbi: 1 wave per batch + 4-deep feats prefetch ----------------
__global__ __launch_bounds__(256) void k_viterbi(const float* __restrict__ feats,
                        const float* __restrict__ trans, float* __restrict__ out){
  __shared__ unsigned char bp[4][512][12];
  const int wave = threadIdx.x >> 6, lane = threadIdx.x & 63;
  const int b = blockIdx.x*4 + wave;
  const int j = lane;
  float tr[11];
  float fv;
  if (j < 11){
    #pragma unroll
    for (int p = 0; p < 11; ++p) tr[p] = trans[j*11 + p];
    fv = (j == 9) ? 0.f : -1000.f;
  } else {
    #pragma unroll
    for (int p = 0; p < 11; ++p) tr[p] = -1e30f;
    fv = -1e30f;
  }
  const float* fb = feats + ((size_t)b*512)*11 + j;
  float f0 = (j < 11) ? fb[0*11] : 0.f;
  float f1 = (j < 11) ? fb[1*11] : 0.f;
  float f2 = (j < 11) ? fb[2*11] : 0.f;
  float f3 = (j < 11) ? fb[3*11] : 0.f;
#define VSTEP(TT, FREG) {                                            \
    float best = -1e38f; int bestp = 0;                              \
    _Pragma("unroll")                                                \
    for (int p = 0; p < 11; ++p){                                    \
      float v = __shfl(fv, p, 64) + tr[p];                           \
      if (v > best){ best = v; bestp = p; }                          \
    }                                                                \
    fv = best + FREG;                                                \
    if (j < 11) bp[wave][TT][j] = (unsigned char)bestp; }
  for (int t = 0; t < 512; t += 4){
    VSTEP(t+0, f0); f0 = (j < 11 && t+4 < 512) ? fb[(size_t)(t+4)*11] : 0.f;
    VSTEP(t+1, f1); f1 = (j < 11 && t+5 < 512) ? fb[(size_t)(t+5)*11] : 0.f;
    VSTEP(t+2, f2); f2 = (j < 11 && t+6 < 512) ? fb[(size_t)(t+6)*11] : 0.f;
    VSTEP(t+3, f3); f3 = (j < 11 && t+7 < 512) ? fb[(size_t)(t+7)*11] : 0.f;
  }
#undef VSTEP
  float term = (j < 11) ? fv + trans[10*11 + j] : -1e38f;
  float best = -1e38f; int bestp = 0;
  #pragma unroll
  for (int p = 0; p < 11; ++p){
    float v = __shfl(term, p, 64);
    if (v > best){ best = v; bestp = p; }
  }
  if (lane == 0){
    out[b] = best;
    float* path = out + 64 + (size_t)b*512;
    int cur = bestp;
    path[511] = (float)cur;
    for (int t = 511; t >= 1; --t){
      cur = bp[wave][t][cur];
      path[t-1] = (float)cur;
    }
  }
}

extern "C" void kernel_launch(void* const* d_in, const int* in_sizes, int n_in,
                              void* d_out, int out_size, void* d_ws, size_t ws_size,
                              hipStream_t stream){
  const int*   sent  = (const int*)d_in[0];
  const float* emb   = (const float*)d_in[2];
  const float* fcw   = (const float*)d_in[3];
  const float* fcb   = (const float*)d_in[4];
  const float* trans = (const float*)d_in[5];
  const float* wih0f = (const float*)d_in[6];
  const float* whh0f = (const float*)d_in[7];
  const float* b0f   = (const float*)d_in[8];
  const float* wih0b = (const float*)d_in[9];
  const float* whh0b = (const float*)d_in[10];
  const float* b0b   = (const float*)d_in[11];
  const float* wih1f = (const float*)d_in[12];
  const float* whh1f = (const float*)d_in[13];
  const float* b1f   = (const float*)d_in[14];
  const float* wih1b = (const float*)d_in[15];
  const float* whh1b = (const float*)d_in[16];
  const float* b1b   = (const float*)d_in[17];

  float* ws = (float*)d_ws;
  // -------- fixed region (hx grown to stamped u64 slots: 131072 floats; flags gone) --------
  const size_t o_wT0f = 0;                         // 304*1024
  const size_t o_wT0b = o_wT0f + 311296;
  const size_t o_wT1f = o_wT0b + 311296;           // 512*1024
  const size_t o_wT1b = o_wT1f + 524288;
  const size_t o_hx   = o_wT1b + 524288;           // 128 chains*2 hh*2 par*128 u64 = 131072 fl
  const size_t o_hs   = o_hx   + 131072;           // hsave 32768
  const size_t o_cs   = o_hs   + 32768;            // csave 32768
  const size_t o_feat = o_cs   + 32768;            // 32768*11 = 360448
  const size_t o_var  = o_feat + 360448;
  float* wT0f = ws + o_wT0f;
  float* wT0b = ws + o_wT0b;
  float* wT1f = ws + o_wT1f;
  float* wT1b = ws + o_wT1b;
  unsigned long long* hx = (unsigned long long*)(ws + o_hx);
  float* hsave = ws + o_hs;
  float* csave = ws + o_cs;
  float* feats = ws + o_feat;

  // -------- adaptive (C batches, T timesteps) slab sizing; big-T first to
  // amortize per-dispatch weight prologue (512KB/block) --------
  int C = 8, T = 32, logT = 5;
  {
    const int cc[12] = {64, 64, 64, 64, 64, 32, 32, 16, 16, 8, 8, 8};
    const int tt[12] = {512,256,128, 64, 32, 32, 16, 32, 16, 64, 32, 16};
    const int lt[12] = {  9,  8,  7,  6,  5,  5,  4,  5,  4,  6,  5, 4};
    for (int i = 0; i < 12; ++i){
      size_t need = (o_var + (size_t)cc[i]*tt[i]*2656 + (size_t)cc[i]*262144)*4;
      if (need <= ws_size){ C = cc[i]; T = tt[i]; logT = lt[i]; break; }
    }
  }
  const int Tm1 = T - 1, S = 512 / T;
  float* XF  = ws + o_var;                        // [C*T,304]  (layer0)
  float* XB  = XF + (size_t)C*T*304;
  float* xwF = XB + (size_t)C*T*304;              // [C*T,1024]
  float* xwB = xwF + (size_t)C*T*1024;
  float* h0  = xwB + (size_t)C*T*1024;            // [C,512,512] fp32
  float* h1s = XF;                                // alias: [C,T,512] (layer1 slab)

  hipLaunchKernelGGL(k_prepw, dim3(512), dim3(256), 0, stream, wih0f, wT0f, 300, 304);
  hipLaunchKernelGGL(k_prepw, dim3(512), dim3(256), 0, stream, wih0b, wT0b, 300, 304);
  hipLaunchKernelGGL(k_prepw, dim3(512), dim3(256), 0, stream, wih1f, wT1f, 512, 512);
  hipLaunchKernelGGL(k_prepw, dim3(512), dim3(256), 0, stream, wih1b, wT1b, 512, 512);
  hipLaunchKernelGGL(k_zero,  dim3(512), dim3(256), 0, stream, feats, 360448);

  for (int b0 = 0; b0 < 64; b0 += C){
    for (int layer = 0; layer < 2; ++layer){
      // zero hx (stamps must restart below epoch+1) + hsave + csave
      hipLaunchKernelGGL(k_zero, dim3(256), dim3(256), 0, stream, ws + o_hx, 131072 + 32768 + 32768);
      const float* whF = layer ? whh1f : whh0f;
      const float* whB = layer ? whh1b : whh0b;
      for (int sl = 0; sl < S; ++sl){
        const int sF = sl, sB = S - 1 - sl;
        const int M = C*T;
        if (layer == 0){
          int total = C*T*76;
          hipLaunchKernelGGL(k_gather, dim3((total+255)/256), dim3(256), 0, stream,
                             sent, emb, (float4*)XF, b0, sF*T, logT, Tm1, total);
          hipLaunchKernelGGL(k_gather, dim3((total+255)/256), dim3(256), 0, stream,
                             sent, emb, (float4*)XB, b0, sB*T, logT, Tm1, total);
          hipLaunchKernelGGL(k_gemm2, dim3(8, M/128, 2), dim3(256), 0, stream,
                             XF, XB, 304, 19, T, 0, 0, logT, Tm1,
                             wT0f, wT0b, b0f, b0b, xwF, xwB);
        } else {
          hipLaunchKernelGGL(k_gemm2, dim3(8, M/128, 2), dim3(256), 0, stream,
                             h0, h0, 512, 32, 512, sF*T, sB*T, logT, Tm1,
                             wT1f, wT1b, b1f, b1b, xwF, xwB);
        }
        {
          const float *xF = xwF, *xB = xwB, *wF = whF, *wB = whB;
          float* hop = layer ? h1s : h0;
          int hBs  = layer ? T*512 : 512*512;
          int tOF  = layer ? 0 : sF*T;
          int tOB  = layer ? 0 : sB*T;
          int Tk = T, ep = sl*T;
          unsigned long long* hxp = hx;
          float *hsp = hsave, *csp = csave;
          void* args[] = {(void*)&xF, (void*)&xB, (void*)&wF, (void*)&wB,
                          (void*)&hop, (void*)&hBs, (void*)&tOF, (void*)&tOB,
                          (void*)&Tk, (void*)&ep,
                          (void*)&hxp, (void*)&hsp, (void*)&csp};
          hipLaunchCooperativeKernel((const void*)k_lstm2s, dim3(C*4), dim3(512), args, 0, stream);
        }
        if (layer == 1){
          hipLaunchKernelGGL(k_feats_half, dim3(C*T/4), dim3(256), 0, stream,
                             h1s, fcw, fcb, feats, b0, logT, Tm1, sF*T, 0);
          hipLaunchKernelGGL(k_feats_half, dim3(C*T/4), dim3(256), 0, stream,
                             h1s, fcw, fcb, feats, b0, logT, Tm1, sB*T, 1);
        }
      }
    }
  }
  hipLaunchKernelGGL(k_viterbi, dim3(16), dim3(256), 0, stream, feats, trans, (float*)d_out);
}